// Round 9
// baseline (727.155 us; speedup 1.0000x reference)
//
#include <hip/hip_runtime.h>

typedef __attribute__((ext_vector_type(8))) short bf16x8;
typedef __attribute__((ext_vector_type(4))) float f32x4;
typedef __attribute__((ext_vector_type(4))) unsigned short u16x4;
typedef __attribute__((ext_vector_type(4))) unsigned int u32x4;
typedef __attribute__((ext_vector_type(2))) unsigned int u32x2;

#define DEVFN static __device__ __forceinline__

DEVFN unsigned short f2b(float f) {   // f32 -> bf16, round-to-nearest-even
  union { float f; unsigned u; } x; x.f = f;
  unsigned r = x.u + 0x7FFFu + ((x.u >> 16) & 1u);
  return (unsigned short)(r >> 16);
}

DEVFN unsigned cvtpk(float lo, float hi) {  // {bf16(hi)<<16 | bf16(lo)}
  unsigned r;
  asm("v_cvt_pk_bf16_f32 %0, %1, %2" : "=v"(r) : "v"(lo), "v"(hi));
  return r;
}

DEVFN void gll16(const void* g, void* l) {  // async global->LDS, 16B per lane
  __builtin_amdgcn_global_load_lds(
      (const __attribute__((address_space(1))) unsigned int*)g,
      (__attribute__((address_space(3))) unsigned int*)l, 16, 0, 0);
}

#define MFMA16(a, b, c) __builtin_amdgcn_mfma_f32_16x16x32_bf16((a), (b), (c), 0, 0, 0)

// ---------------- prep: cast + transpose weights to bf16 ----------------
// wqkvT [1152][384] (q sector pre-scaled by 0.125), woT, w1T, w2T
__global__ __launch_bounds__(256) void prep_kernel(
    const float* __restrict__ Wq, const float* __restrict__ Wk, const float* __restrict__ Wv,
    const float* __restrict__ Wo, const float* __restrict__ W1, const float* __restrict__ W2,
    short* __restrict__ wqkvT, short* __restrict__ woT,
    short* __restrict__ w1T, short* __restrict__ w2T)
{
  int idx = blockIdx.x * 256 + threadIdx.x;
  if (idx < 442368) {
    int n = idx / 384, kk = idx - n * 384;
    int sec = n / 384, ww = n - sec * 384;
    const float* s = sec == 0 ? Wq : (sec == 1 ? Wk : Wv);
    float sc = (sec == 0) ? 0.125f : 1.0f;
    wqkvT[idx] = (short)f2b(s[kk * 384 + ww] * sc);
  } else if (idx < 589824) {
    int j = idx - 442368;
    int n = j / 384, kk = j - n * 384;
    woT[j] = (short)f2b(Wo[kk * 384 + n]);
  } else if (idx < 1179648) {
    int j = idx - 589824;
    int n = j / 384, kk = j - n * 384;
    w1T[j] = (short)f2b(W1[kk * 1536 + n]);
  } else if (idx < 1769472) {
    int j = idx - 1179648;
    int n = j / 1536, kk = j - n * 1536;
    w2T[j] = (short)f2b(W2[kk * 384 + n]);
  }
}

// ---------------- LayerNorm: f32 in -> bf16 out, 1 wave per row of 384 ----
__global__ __launch_bounds__(256) void ln_kernel(
    const float* __restrict__ x, const float* __restrict__ g, const float* __restrict__ b,
    short* __restrict__ out)
{
  int row = blockIdx.x * 4 + (threadIdx.x >> 6);
  int l = threadIdx.x & 63;
  const float* xr = x + (size_t)row * 384;
  float v[6], s = 0.f, s2 = 0.f;
  #pragma unroll
  for (int i = 0; i < 6; ++i) { v[i] = xr[l + 64 * i]; s += v[i]; s2 += v[i] * v[i]; }
  #pragma unroll
  for (int m = 1; m < 64; m <<= 1) { s += __shfl_xor(s, m); s2 += __shfl_xor(s2, m); }
  float mu = s * (1.f / 384.f);
  float rs = rsqrtf(s2 * (1.f / 384.f) - mu * mu + 1e-5f);
  short* orow = out + (size_t)row * 384;
  #pragma unroll
  for (int i = 0; i < 6; ++i) {
    int c = l + 64 * i;
    orow[c] = (short)f2b((v[i] - mu) * rs * g[c] + b[c]);
  }
}

// ---------------- GEMM: C[M,N] = A[M,K] * BT[N,K]^T, bf16 MFMA ------------
// 256x128 tile, BK=64, 512 threads = 8 waves (4x2), wave = 64x64 (4x4 frags).
// EPI 0: QKV split (weights pre-scaled; v stored [B,H,D,T])   [R5-exact]
// EPI 1: f32 out = acc + bias[col] + resid[row,col]
template<int EPI>
__global__ __launch_bounds__(512) void gemm_bt(
    const short* __restrict__ A, const short* __restrict__ BT,
    int K, int kt, int N, int nx,
    const float* __restrict__ bias, const float* __restrict__ resid,
    float* __restrict__ fout,
    short* __restrict__ qb, short* __restrict__ kb, short* __restrict__ vb)
{
  __shared__ short As[256 * 64];
  __shared__ short Bs[128 * 64];
  const int tid = threadIdx.x;
  const int l = tid & 63, w = tid >> 6;
  const int cl = l & 15, rq = l >> 4;
  const int wr = (w >> 1) * 64, wc = (w & 1) * 64;

  // bijective XCD-chunk swizzle
  const int nwg = gridDim.x, bid = blockIdx.x;
  const int q8 = nwg >> 3, r8 = nwg & 7;
  const int xcd = bid & 7, ii = bid >> 3;
  const int wg = (xcd < r8) ? xcd * (q8 + 1) + ii : r8 * (q8 + 1) + (xcd - r8) * q8 + ii;
  const int bx = wg % nx, by = wg / nx;

  const int m0 = by * 256, n0 = bx * 128;
  const short* Ab = A + (size_t)m0 * K;
  const short* Bb = BT + (size_t)n0 * K;

  f32x4 acc[4][4] = {};

  for (int ks = 0; ks < kt; ++ks) {
    const int k0 = ks * 64;
    __syncthreads();
    #pragma unroll
    for (int i = 0; i < 4; ++i) {
      int slot = i * 512 + tid;
      int row = slot >> 3, g = slot & 7;
      int gs = g ^ (row & 7);
      gll16(Ab + (size_t)row * K + k0 + gs * 8, &As[slot * 8]);
    }
    #pragma unroll
    for (int i = 0; i < 2; ++i) {
      int slot = i * 512 + tid;
      int row = slot >> 3, g = slot & 7;
      int gs = g ^ (row & 7);
      gll16(Bb + (size_t)row * K + k0 + gs * 8, &Bs[slot * 8]);
    }
    __syncthreads();
    #pragma unroll
    for (int kk = 0; kk < 2; ++kk) {
      bf16x8 af[4], bfr[4];
      #pragma unroll
      for (int m = 0; m < 4; ++m) {
        int row = wr + m * 16 + cl;
        af[m] = *(const bf16x8*)&As[row * 64 + (((kk * 4 + rq) ^ (row & 7)) * 8)];
      }
      #pragma unroll
      for (int n = 0; n < 4; ++n) {
        int row = wc + n * 16 + cl;
        bfr[n] = *(const bf16x8*)&Bs[row * 64 + (((kk * 4 + rq) ^ (row & 7)) * 8)];
      }
      #pragma unroll
      for (int m = 0; m < 4; ++m)
        #pragma unroll
        for (int n = 0; n < 4; ++n)
          acc[m][n] = MFMA16(af[m], bfr[n], acc[m][n]);
    }
  }

  const int gr0 = m0 + wr, gc0 = n0 + wc;
  #pragma unroll
  for (int m = 0; m < 4; ++m) {
    #pragma unroll
    for (int n = 0; n < 4; ++n) {
      int col = gc0 + n * 16 + cl;
      int rbase = gr0 + m * 16 + rq * 4;
      if constexpr (EPI == 0) {
        int sec = col / 384;
        int wcol = col - sec * 384;
        int hh = wcol >> 6, d = wcol & 63;
        int bidx = rbase >> 8, t0 = rbase & 255;
        if (sec == 2) {
          u16x4 pk;
          #pragma unroll
          for (int r = 0; r < 4; ++r) pk[r] = f2b(acc[m][n][r]);
          *(u16x4*)&vb[((size_t)(bidx * 6 + hh) * 64 + d) * 256 + t0] = pk;
        } else {
          short* dst = (sec == 0) ? qb : kb;
          #pragma unroll
          for (int r = 0; r < 4; ++r)
            dst[((size_t)(bidx * 6 + hh) * 256 + t0 + r) * 64 + d] = (short)f2b(acc[m][n][r]);
        }
      } else {
        #pragma unroll
        for (int r = 0; r < 4; ++r) {
          size_t ix = (size_t)(rbase + r) * N + col;
          fout[ix] = acc[m][n][r] + bias[col] + resid[ix];
        }
      }
    }
  }
}

// ---------------- fused FF: out += relu(h2 @ W1 + b1) @ W2 + b2 -----------
// 1 block = 64 token rows. 512 thr = 8 waves. h2 rows staged to LDS ONCE
// (48KB swizzled); W1/W2 fragments read DIRECTLY from global (L2-resident).
// Loop 12 ff-chunks of 128: phase A act-chunk in regs (swapped MFMA), relu+b1,
// cvtpk -> swizzled Acts (16KB); phase B acc += Acts @ W2-slice.
// 2 barriers per chunk; LDS 64KB -> 2 blocks/CU.
__global__ __launch_bounds__(512, 4) void ff_fused(
    const short* __restrict__ h2,      // [65536][384] bf16
    const short* __restrict__ w1T,     // [1536][384]
    const short* __restrict__ w2T,     // [384][1536]
    const float* __restrict__ b1, const float* __restrict__ b2,
    float* __restrict__ out)           // [65536][384] f32 (residual in-place)
{
  __shared__ short As[64 * 384];     // h2 rows; 48 granules/row, low3 XOR row
  __shared__ short Acts[64 * 128];   // act chunk [tok][ff], swizzled
  const int tid = threadIdx.x;
  const int l = tid & 63, w = tid >> 6;
  const int cl = l & 15, rq = l >> 4;
  const int wm = w >> 2, wn = w & 3;   // wave rows wm*32.., cols wn*96..
  const int m0 = blockIdx.x * 64;

  // stage h2 rows once: 3072 granules of 16B, pre-swizzled source
  #pragma unroll
  for (int i = 0; i < 6; ++i) {
    int slot = i * 512 + tid;
    int row = slot / 48, g = slot - row * 48;
    int gs = (g & 56) | ((g ^ row) & 7);
    gll16(h2 + (size_t)(m0 + row) * 384 + gs * 8, &As[slot * 8]);
  }
  __syncthreads();

  f32x4 acc[2][6] = {};  // out[row=wm*32+m*16+4rq+r][col=wn*96+n*16+cl]

  for (int c = 0; c < 12; ++c) {
    // ---- phase A: act[0..63][c*128 .. +127] ----
    f32x4 aacc[4] = {};
    const short* w1p = w1T + (size_t)(c * 128 + w * 16 + cl) * 384;
    #pragma unroll
    for (int ks = 0; ks < 6; ++ks) {
      #pragma unroll
      for (int kk = 0; kk < 2; ++kk) {
        bf16x8 w1f = *(const bf16x8*)&w1p[ks * 64 + (kk * 4 + rq) * 8];
        int gran = ks * 8 + kk * 4 + rq;
        #pragma unroll
        for (int m8 = 0; m8 < 4; ++m8) {
          int arow = m8 * 16 + cl;
          bf16x8 hf = *(const bf16x8*)&As[arow * 384 +
              (((gran & 56) | ((gran ^ arow) & 7)) * 8)];
          aacc[m8] = MFMA16(w1f, hf, aacc[m8]);  // lane: ff=w*16+4rq+r, tok=arow
        }
      }
    }
    __syncthreads();   // prev chunk's phase B done reading Acts
    // relu + b1, pack, write Acts (ff byte-pos within row = w*16+rq*4 shorts)
    f32x4 b1v = *(const f32x4*)&b1[c * 128 + w * 16 + 4 * rq];
    #pragma unroll
    for (int m8 = 0; m8 < 4; ++m8) {
      int row = m8 * 16 + cl;
      int gran2 = 2 * w + (rq >> 1);
      int off = row * 128 + ((gran2 ^ (row & 7)) * 8) + ((rq & 1) * 4);
      u32x2 pw;
      pw[0] = cvtpk(fmaxf(aacc[m8][0] + b1v[0], 0.f), fmaxf(aacc[m8][1] + b1v[1], 0.f));
      pw[1] = cvtpk(fmaxf(aacc[m8][2] + b1v[2], 0.f), fmaxf(aacc[m8][3] + b1v[3], 0.f));
      *(u32x2*)&Acts[off] = pw;
    }
    __syncthreads();   // Acts visible to all waves
    // ---- phase B: acc += Acts @ W2[c*128 .. +127][all 384 cols] ----
    #pragma unroll
    for (int fk = 0; fk < 2; ++fk) {
      #pragma unroll
      for (int kk = 0; kk < 2; ++kk) {
        int gran = fk * 8 + kk * 4 + rq;
        bf16x8 af[2], bfr[6];
        #pragma unroll
        for (int m = 0; m < 2; ++m) {
          int row = wm * 32 + m * 16 + cl;
          af[m] = *(const bf16x8*)&Acts[row * 128 + ((gran ^ (row & 7)) * 8)];
        }
        #pragma unroll
        for (int n = 0; n < 6; ++n)
          bfr[n] = *(const bf16x8*)&w2T[(size_t)(wn * 96 + n * 16 + cl) * 1536 +
                                        c * 128 + fk * 64 + (kk * 4 + rq) * 8];
        #pragma unroll
        for (int m = 0; m < 2; ++m)
          #pragma unroll
          for (int n = 0; n < 6; ++n)
            acc[m][n] = MFMA16(af[m], bfr[n], acc[m][n]);
      }
    }
  }
  // epilogue: out = acc + b2 + out (residual RMW, own elements)
  #pragma unroll
  for (int m = 0; m < 2; ++m) {
    #pragma unroll
    for (int n = 0; n < 6; ++n) {
      int col = wn * 96 + n * 16 + cl;
      int rbase = m0 + wm * 32 + m * 16 + 4 * rq;
      #pragma unroll
      for (int r = 0; r < 4; ++r) {
        size_t ix = (size_t)(rbase + r) * 384 + col;
        out[ix] = acc[m][n][r] + b2[col] + out[ix];
      }
    }
  }
}

// ---------------- attention: 1 block = ONE (b,h), 1024 thr = 16 waves -----
// (verbatim from R5, passing)
__global__ __launch_bounds__(1024) void attn_kernel(
    const short* __restrict__ qg, const short* __restrict__ kg,
    const short* __restrict__ vg, short* __restrict__ og)
{
  __shared__ short Ks[256 * 64];   // [s][d], swizzled (8 granules/row)
  __shared__ short Vs[64 * 256];   // [d][s], swizzled (32 granules/row, low3)
  const int tid = threadIdx.x;
  const int bh = blockIdx.x;
  const int w = tid >> 6, l = tid & 63;
  const int cl = l & 15, rq = l >> 4;
  const short* kgb = kg + (size_t)bh * 16384;
  const short* vgb = vg + (size_t)bh * 16384;
  #pragma unroll
  for (int i = 0; i < 2; ++i) {
    int slot = i * 1024 + tid;
    int row = slot >> 3, g = slot & 7;
    gll16(kgb + row * 64 + (g ^ (row & 7)) * 8, &Ks[slot * 8]);
  }
  #pragma unroll
  for (int i = 0; i < 2; ++i) {
    int slot = i * 1024 + tid;
    int row = slot >> 5, g = slot & 31;
    int gs = (g & 24) | ((g ^ row) & 7);
    gll16(vgb + row * 256 + gs * 8, &Vs[slot * 8]);
  }
  const int qrow = w * 16 + cl;
  const bf16x8* qp = (const bf16x8*)(qg + ((size_t)bh * 256 + qrow) * 64 + rq * 8);
  bf16x8 qf0 = qp[0], qf1 = qp[4];
  const int b = bh / 6, hh = bh - b * 6;
  __syncthreads();

  f32x4 s[16] = {};
  #pragma unroll
  for (int c = 0; c < 16; ++c) {
    int srow = c * 16 + cl;
    bf16x8 k0 = *(const bf16x8*)&Ks[srow * 64 + ((rq ^ (srow & 7)) * 8)];
    bf16x8 k1 = *(const bf16x8*)&Ks[srow * 64 + (((4 + rq) ^ (srow & 7)) * 8)];
    s[c] = MFMA16(k0, qf0, s[c]);
    s[c] = MFMA16(k1, qf1, s[c]);
  }
  float mr[8];
  #pragma unroll
  for (int c = 0; c < 8; ++c)
    mr[c] = fmaxf(fmaxf(fmaxf(s[2*c][0], s[2*c][1]), fmaxf(s[2*c][2], s[2*c][3])),
                  fmaxf(fmaxf(s[2*c+1][0], s[2*c+1][1]), fmaxf(s[2*c+1][2], s[2*c+1][3])));
  float m = fmaxf(fmaxf(fmaxf(mr[0], mr[1]), fmaxf(mr[2], mr[3])),
                  fmaxf(fmaxf(mr[4], mr[5]), fmaxf(mr[6], mr[7])));
  m = fmaxf(m, __shfl_xor(m, 16));
  m = fmaxf(m, __shfl_xor(m, 32));
  float tc[16];
  #pragma unroll
  for (int c = 0; c < 16; ++c) {
    #pragma unroll
    for (int r = 0; r < 4; ++r) s[c][r] = __expf(s[c][r] - m);
    tc[c] = (s[c][0] + s[c][1]) + (s[c][2] + s[c][3]);
  }
  float t = ((tc[0]+tc[1])+(tc[2]+tc[3])) + ((tc[4]+tc[5])+(tc[6]+tc[7]))
          + ((tc[8]+tc[9])+(tc[10]+tc[11])) + ((tc[12]+tc[13])+(tc[14]+tc[15]));
  t += __shfl_xor(t, 16);
  t += __shfl_xor(t, 32);
  const float inv = 1.f / t;   // for qrow = cl

  f32x4 oacc[4] = {};
  const int idx1 = (((2 * rq) & 3) * 16 + cl) << 2;
  const int idx2 = (((2 * rq + 1) & 3) * 16 + cl) << 2;
  const bool up = rq >= 2;
  #pragma unroll
  for (int ch = 0; ch < 8; ++ch) {
    int X0 = (int)cvtpk(s[2*ch][0], s[2*ch][1]);
    int X1 = (int)cvtpk(s[2*ch][2], s[2*ch][3]);
    int X2 = (int)cvtpk(s[2*ch+1][0], s[2*ch+1][1]);
    int X3 = (int)cvtpk(s[2*ch+1][2], s[2*ch+1][3]);
    int lo0 = __builtin_amdgcn_ds_bpermute(idx1, X0);
    int lo1 = __builtin_amdgcn_ds_bpermute(idx1, X1);
    int hi0 = __builtin_amdgcn_ds_bpermute(idx1, X2);
    int hi1 = __builtin_amdgcn_ds_bpermute(idx1, X3);
    int lo2 = __builtin_amdgcn_ds_bpermute(idx2, X0);
    int lo3 = __builtin_amdgcn_ds_bpermute(idx2, X1);
    int hi2 = __builtin_amdgcn_ds_bpermute(idx2, X2);
    int hi3 = __builtin_amdgcn_ds_bpermute(idx2, X3);
    u32x4 words;
    words[0] = (unsigned)(up ? hi0 : lo0);
    words[1] = (unsigned)(up ? hi1 : lo1);
    words[2] = (unsigned)(up ? hi2 : lo2);
    words[3] = (unsigned)(up ? hi3 : lo3);
    bf16x8 pa = __builtin_bit_cast(bf16x8, words);
    #pragma unroll
    for (int n = 0; n < 4; ++n) {
      int vrow = n * 16 + cl;
      int gg = ch * 4 + rq;
      int gs = (gg & 24) | ((gg ^ vrow) & 7);
      bf16x8 vf = *(const bf16x8*)&Vs[vrow * 256 + gs * 8];
      oacc[n] = MFMA16(pa, vf, oacc[n]);
    }
  }
  float invr[4];
  #pragma unroll
  for (int r = 0; r < 4; ++r) invr[r] = __shfl(inv, 4 * rq + r);
  #pragma unroll
  for (int n = 0; n < 4; ++n) {
    #pragma unroll
    for (int r = 0; r < 4; ++r) {
      int trow = w * 16 + 4 * rq + r;
      og[((size_t)(b * 256 + trow)) * 384 + hh * 64 + n * 16 + cl] =
          (short)f2b(oacc[n][r] * invr[r]);
    }
  }
}

// ---------------- host ----------------
extern "C" void kernel_launch(void* const* d_in, const int* in_sizes, int n_in,
                              void* d_out, int out_size, void* d_ws, size_t ws_size,
                              hipStream_t stream) {
  const float* x   = (const float*)d_in[0];
  const float* Wq  = (const float*)d_in[1];
  const float* Wk  = (const float*)d_in[2];
  const float* Wv  = (const float*)d_in[3];
  const float* Wo  = (const float*)d_in[4];
  const float* bo  = (const float*)d_in[5];
  const float* W1  = (const float*)d_in[6];
  const float* b1  = (const float*)d_in[7];
  const float* W2  = (const float*)d_in[8];
  const float* b2  = (const float*)d_in[9];
  const float* g1  = (const float*)d_in[10];
  const float* be1 = (const float*)d_in[11];
  const float* g2  = (const float*)d_in[12];
  const float* be2 = (const float*)d_in[13];

  char* ws = (char*)d_ws;
  short* wqkvT = (short*)(ws);                 //  884736 B (q sector pre-scaled)
  short* woT   = (short*)(ws + 884736);        //  294912 B
  short* w1T   = (short*)(ws + 1179648);       // 1179648 B
  short* w2T   = (short*)(ws + 2359296);       // 1179648 B
  short* bufA  = (short*)(ws + 3538944);       // shared region (shorts)
  short* h  = bufA;                            // LN1 out [0, 25165824)
  short* q  = bufA + 25165824;                 // [B,H,T,D]
  short* k  = bufA + 50331648;                 // [B,H,T,D]
  short* v  = bufA + 75497472;                 // [B,H,D,T]
  short* o  = bufA;                            // attn out, overlays h
  short* h2 = bufA + 25165824;                 // LN2 out, overlays q (dead)
  float* out = (float*)d_out;                  // residual stream after Wo

  prep_kernel<<<6912, 256, 0, stream>>>(Wq, Wk, Wv, Wo, W1, W2, wqkvT, woT, w1T, w2T);
  ln_kernel<<<16384, 256, 0, stream>>>(x, g1, be1, h);
  // QKV: [65536,384] x [1152,384]^T -> q,k,v   grid 9x256
  gemm_bt<0><<<9 * 256, 512, 0, stream>>>(h, wqkvT, 384, 6, 1152, 9,
      nullptr, nullptr, nullptr, q, k, v);
  attn_kernel<<<1536, 1024, 0, stream>>>(q, k, v, o);
  // Wo: out = o @ Wo + bo + x   grid 3x256
  gemm_bt<1><<<3 * 256, 512, 0, stream>>>(o, woT, 384, 6, 384, 3,
      bo, x, out, nullptr, nullptr, nullptr);
  ln_kernel<<<16384, 256, 0, stream>>>(out, g2, be2, h2);
  // fused FF: out += relu(h2 @ W1 + b1) @ W2 + b2
  ff_fused<<<1024, 512, 0, stream>>>(h2, w1T, w2T, b1, b2, out);
}

// Round 10
// 589.902 us; speedup vs baseline: 1.2327x; 1.2327x over previous
//
#include <hip/hip_runtime.h>

typedef __attribute__((ext_vector_type(8))) short bf16x8;
typedef __attribute__((ext_vector_type(4))) float f32x4;
typedef __attribute__((ext_vector_type(4))) unsigned short u16x4;
typedef __attribute__((ext_vector_type(4))) unsigned int u32x4;
typedef __attribute__((ext_vector_type(2))) unsigned int u32x2;

#define DEVFN static __device__ __forceinline__

DEVFN unsigned short f2b(float f) {   // f32 -> bf16, round-to-nearest-even
  union { float f; unsigned u; } x; x.f = f;
  unsigned r = x.u + 0x7FFFu + ((x.u >> 16) & 1u);
  return (unsigned short)(r >> 16);
}

DEVFN unsigned cvtpk(float lo, float hi) {  // {bf16(hi)<<16 | bf16(lo)}
  unsigned r;
  asm("v_cvt_pk_bf16_f32 %0, %1, %2" : "=v"(r) : "v"(lo), "v"(hi));
  return r;
}

DEVFN void gll16(const void* g, void* l) {  // async global->LDS, 16B per lane
  __builtin_amdgcn_global_load_lds(
      (const __attribute__((address_space(1))) unsigned int*)g,
      (__attribute__((address_space(3))) unsigned int*)l, 16, 0, 0);
}

#define MFMA16(a, b, c) __builtin_amdgcn_mfma_f32_16x16x32_bf16((a), (b), (c), 0, 0, 0)

// ---------------- prep: cast + transpose weights to bf16 ----------------
// wqkvT [1152][384] (q sector pre-scaled by 0.125), woT, w1T, w2T
__global__ __launch_bounds__(256) void prep_kernel(
    const float* __restrict__ Wq, const float* __restrict__ Wk, const float* __restrict__ Wv,
    const float* __restrict__ Wo, const float* __restrict__ W1, const float* __restrict__ W2,
    short* __restrict__ wqkvT, short* __restrict__ woT,
    short* __restrict__ w1T, short* __restrict__ w2T)
{
  int idx = blockIdx.x * 256 + threadIdx.x;
  if (idx < 442368) {
    int n = idx / 384, kk = idx - n * 384;
    int sec = n / 384, ww = n - sec * 384;
    const float* s = sec == 0 ? Wq : (sec == 1 ? Wk : Wv);
    float sc = (sec == 0) ? 0.125f : 1.0f;
    wqkvT[idx] = (short)f2b(s[kk * 384 + ww] * sc);
  } else if (idx < 589824) {
    int j = idx - 442368;
    int n = j / 384, kk = j - n * 384;
    woT[j] = (short)f2b(Wo[kk * 384 + n]);
  } else if (idx < 1179648) {
    int j = idx - 589824;
    int n = j / 384, kk = j - n * 384;
    w1T[j] = (short)f2b(W1[kk * 1536 + n]);
  } else if (idx < 1769472) {
    int j = idx - 1179648;
    int n = j / 1536, kk = j - n * 1536;
    w2T[j] = (short)f2b(W2[kk * 384 + n]);
  }
}

// ---------------- LayerNorm: f32 in -> bf16 out, 1 wave per row of 384 ----
__global__ __launch_bounds__(256) void ln_kernel(
    const float* __restrict__ x, const float* __restrict__ g, const float* __restrict__ b,
    short* __restrict__ out)
{
  int row = blockIdx.x * 4 + (threadIdx.x >> 6);
  int l = threadIdx.x & 63;
  const float* xr = x + (size_t)row * 384;
  float v[6], s = 0.f, s2 = 0.f;
  #pragma unroll
  for (int i = 0; i < 6; ++i) { v[i] = xr[l + 64 * i]; s += v[i]; s2 += v[i] * v[i]; }
  #pragma unroll
  for (int m = 1; m < 64; m <<= 1) { s += __shfl_xor(s, m); s2 += __shfl_xor(s2, m); }
  float mu = s * (1.f / 384.f);
  float rs = rsqrtf(s2 * (1.f / 384.f) - mu * mu + 1e-5f);
  short* orow = out + (size_t)row * 384;
  #pragma unroll
  for (int i = 0; i < 6; ++i) {
    int c = l + 64 * i;
    orow[c] = (short)f2b((v[i] - mu) * rs * g[c] + b[c]);
  }
}

// ---------------- GEMM: C[M,N] = A[M,K] * BT[N,K]^T, bf16 MFMA ------------
// 256x128 tile, BK=64, 512 threads = 8 waves (4x2), wave = 64x64 (4x4 frags).
// EPI 0: QKV split (weights pre-scaled; v stored [B,H,D,T])   [R5-exact]
// EPI 1: f32 out = acc + bias[col] + resid[row,col]
template<int EPI>
__global__ __launch_bounds__(512) void gemm_bt(
    const short* __restrict__ A, const short* __restrict__ BT,
    int K, int kt, int N, int nx,
    const float* __restrict__ bias, const float* __restrict__ resid,
    float* __restrict__ fout,
    short* __restrict__ qb, short* __restrict__ kb, short* __restrict__ vb)
{
  __shared__ short As[256 * 64];
  __shared__ short Bs[128 * 64];
  const int tid = threadIdx.x;
  const int l = tid & 63, w = tid >> 6;
  const int cl = l & 15, rq = l >> 4;
  const int wr = (w >> 1) * 64, wc = (w & 1) * 64;

  // bijective XCD-chunk swizzle
  const int nwg = gridDim.x, bid = blockIdx.x;
  const int q8 = nwg >> 3, r8 = nwg & 7;
  const int xcd = bid & 7, ii = bid >> 3;
  const int wg = (xcd < r8) ? xcd * (q8 + 1) + ii : r8 * (q8 + 1) + (xcd - r8) * q8 + ii;
  const int bx = wg % nx, by = wg / nx;

  const int m0 = by * 256, n0 = bx * 128;
  const short* Ab = A + (size_t)m0 * K;
  const short* Bb = BT + (size_t)n0 * K;

  f32x4 acc[4][4] = {};

  for (int ks = 0; ks < kt; ++ks) {
    const int k0 = ks * 64;
    __syncthreads();
    #pragma unroll
    for (int i = 0; i < 4; ++i) {
      int slot = i * 512 + tid;
      int row = slot >> 3, g = slot & 7;
      int gs = g ^ (row & 7);
      gll16(Ab + (size_t)row * K + k0 + gs * 8, &As[slot * 8]);
    }
    #pragma unroll
    for (int i = 0; i < 2; ++i) {
      int slot = i * 512 + tid;
      int row = slot >> 3, g = slot & 7;
      int gs = g ^ (row & 7);
      gll16(Bb + (size_t)row * K + k0 + gs * 8, &Bs[slot * 8]);
    }
    __syncthreads();
    #pragma unroll
    for (int kk = 0; kk < 2; ++kk) {
      bf16x8 af[4], bfr[4];
      #pragma unroll
      for (int m = 0; m < 4; ++m) {
        int row = wr + m * 16 + cl;
        af[m] = *(const bf16x8*)&As[row * 64 + (((kk * 4 + rq) ^ (row & 7)) * 8)];
      }
      #pragma unroll
      for (int n = 0; n < 4; ++n) {
        int row = wc + n * 16 + cl;
        bfr[n] = *(const bf16x8*)&Bs[row * 64 + (((kk * 4 + rq) ^ (row & 7)) * 8)];
      }
      #pragma unroll
      for (int m = 0; m < 4; ++m)
        #pragma unroll
        for (int n = 0; n < 4; ++n)
          acc[m][n] = MFMA16(af[m], bfr[n], acc[m][n]);
    }
  }

  const int gr0 = m0 + wr, gc0 = n0 + wc;
  #pragma unroll
  for (int m = 0; m < 4; ++m) {
    #pragma unroll
    for (int n = 0; n < 4; ++n) {
      int col = gc0 + n * 16 + cl;
      int rbase = gr0 + m * 16 + rq * 4;
      if constexpr (EPI == 0) {
        int sec = col / 384;
        int wcol = col - sec * 384;
        int hh = wcol >> 6, d = wcol & 63;
        int bidx = rbase >> 8, t0 = rbase & 255;
        if (sec == 2) {
          u16x4 pk;
          #pragma unroll
          for (int r = 0; r < 4; ++r) pk[r] = f2b(acc[m][n][r]);
          *(u16x4*)&vb[((size_t)(bidx * 6 + hh) * 64 + d) * 256 + t0] = pk;
        } else {
          short* dst = (sec == 0) ? qb : kb;
          #pragma unroll
          for (int r = 0; r < 4; ++r)
            dst[((size_t)(bidx * 6 + hh) * 256 + t0 + r) * 64 + d] = (short)f2b(acc[m][n][r]);
        }
      } else {
        #pragma unroll
        for (int r = 0; r < 4; ++r) {
          size_t ix = (size_t)(rbase + r) * N + col;
          fout[ix] = acc[m][n][r] + bias[col] + resid[ix];
        }
      }
    }
  }
}

// ---------------- fused FF: out += relu(h2 @ W1 + b1) @ W2 + b2 -----------
// 1 block = 64 token rows, 512 thr = 8 waves. h2 staged to LDS once (48KB).
// Wave owns ALL 64 rows x 48 cols (acc[4][3]).
// Phase A (per 128-ff chunk): W1 frags from global, software-pipelined over
// ks (load ks+1 while MFMA ks); act -> relu+b1 -> cvtpk -> swizzled Acts.
// Phase B: per fk hoist 6 W2 frags (one latency) then 24 MFMAs; af from LDS.
// 2 barriers/chunk; LDS 64KB -> 2 blocks/CU.
__global__ __launch_bounds__(512, 4) void ff_fused(
    const short* __restrict__ h2,      // [65536][384] bf16
    const short* __restrict__ w1T,     // [1536][384]
    const short* __restrict__ w2T,     // [384][1536]
    const float* __restrict__ b1, const float* __restrict__ b2,
    float* __restrict__ out)           // [65536][384] f32 (residual in-place)
{
  __shared__ short As[64 * 384];     // h2 rows; 48 granules/row, low3 XOR row
  __shared__ short Acts[64 * 128];   // act chunk [tok][ff], swizzled
  const int tid = threadIdx.x;
  const int l = tid & 63, w = tid >> 6;
  const int cl = l & 15, rq = l >> 4;
  const int m0 = blockIdx.x * 64;

  // stage h2 rows once: 3072 granules of 16B, pre-swizzled source
  #pragma unroll
  for (int i = 0; i < 6; ++i) {
    int slot = i * 512 + tid;
    int row = slot / 48, g = slot - row * 48;
    int gs = (g & 56) | ((g ^ row) & 7);
    gll16(h2 + (size_t)(m0 + row) * 384 + gs * 8, &As[slot * 8]);
  }
  __syncthreads();

  f32x4 acc[4][3] = {};  // out[row=m*16+4rq+r][col=w*48+n*16+cl]

  for (int c = 0; c < 12; ++c) {
    // ---- phase A: act[0..63][c*128 .. +127], sw-pipelined W1 frags ----
    f32x4 aacc[4] = {};
    const short* w1p = w1T + (size_t)(c * 128 + w * 16 + cl) * 384;
    bf16x8 w0 = *(const bf16x8*)&w1p[rq * 8];
    bf16x8 w1 = *(const bf16x8*)&w1p[32 + rq * 8];
    #pragma unroll
    for (int ks = 0; ks < 6; ++ks) {
      bf16x8 nx0, nx1;
      if (ks < 5) {
        nx0 = *(const bf16x8*)&w1p[(ks + 1) * 64 + rq * 8];
        nx1 = *(const bf16x8*)&w1p[(ks + 1) * 64 + 32 + rq * 8];
      }
      #pragma unroll
      for (int kk = 0; kk < 2; ++kk) {
        bf16x8 w1f = kk ? w1 : w0;
        int gran = ks * 8 + kk * 4 + rq;
        #pragma unroll
        for (int m8 = 0; m8 < 4; ++m8) {
          int arow = m8 * 16 + cl;
          bf16x8 hf = *(const bf16x8*)&As[arow * 384 +
              (((gran & 56) | ((gran ^ arow) & 7)) * 8)];
          aacc[m8] = MFMA16(w1f, hf, aacc[m8]);  // lane: ff=w*16+4rq+r, tok=arow
        }
      }
      w0 = nx0; w1 = nx1;
    }
    __syncthreads();   // prev chunk's phase B done reading Acts
    // relu + b1, pack, write Acts
    f32x4 b1v = *(const f32x4*)&b1[c * 128 + w * 16 + 4 * rq];
    #pragma unroll
    for (int m8 = 0; m8 < 4; ++m8) {
      int row = m8 * 16 + cl;
      int gran2 = 2 * w + (rq >> 1);
      int off = row * 128 + ((gran2 ^ (row & 7)) * 8) + ((rq & 1) * 4);
      u32x2 pw;
      pw[0] = cvtpk(fmaxf(aacc[m8][0] + b1v[0], 0.f), fmaxf(aacc[m8][1] + b1v[1], 0.f));
      pw[1] = cvtpk(fmaxf(aacc[m8][2] + b1v[2], 0.f), fmaxf(aacc[m8][3] + b1v[3], 0.f));
      *(u32x2*)&Acts[off] = pw;
    }
    __syncthreads();   // Acts visible to all waves
    // ---- phase B: acc += Acts @ W2[c*128 .. +127][wave's 48 cols] ----
    #pragma unroll
    for (int fk = 0; fk < 2; ++fk) {
      bf16x8 bfr[2][3];
      #pragma unroll
      for (int kk = 0; kk < 2; ++kk)
        #pragma unroll
        for (int n = 0; n < 3; ++n)
          bfr[kk][n] = *(const bf16x8*)&w2T[(size_t)(w * 48 + n * 16 + cl) * 1536 +
                                            c * 128 + fk * 64 + kk * 32 + rq * 8];
      #pragma unroll
      for (int kk = 0; kk < 2; ++kk) {
        int gran = fk * 8 + kk * 4 + rq;
        bf16x8 af[4];
        #pragma unroll
        for (int m = 0; m < 4; ++m) {
          int row = m * 16 + cl;
          af[m] = *(const bf16x8*)&Acts[row * 128 + ((gran ^ (row & 7)) * 8)];
        }
        #pragma unroll
        for (int m = 0; m < 4; ++m)
          #pragma unroll
          for (int n = 0; n < 3; ++n)
            acc[m][n] = MFMA16(af[m], bfr[kk][n], acc[m][n]);
      }
    }
  }
  // epilogue: out = acc + b2 + out (residual RMW, own elements)
  #pragma unroll
  for (int m = 0; m < 4; ++m) {
    #pragma unroll
    for (int n = 0; n < 3; ++n) {
      int col = w * 48 + n * 16 + cl;
      int rbase = m0 + m * 16 + 4 * rq;
      #pragma unroll
      for (int r = 0; r < 4; ++r) {
        size_t ix = (size_t)(rbase + r) * 384 + col;
        out[ix] = acc[m][n][r] + b2[col] + out[ix];
      }
    }
  }
}

// ---------------- attention: 1 block = ONE (b,h), 1024 thr = 16 waves -----
// (verbatim from R5, passing)
__global__ __launch_bounds__(1024) void attn_kernel(
    const short* __restrict__ qg, const short* __restrict__ kg,
    const short* __restrict__ vg, short* __restrict__ og)
{
  __shared__ short Ks[256 * 64];   // [s][d], swizzled (8 granules/row)
  __shared__ short Vs[64 * 256];   // [d][s], swizzled (32 granules/row, low3)
  const int tid = threadIdx.x;
  const int bh = blockIdx.x;
  const int w = tid >> 6, l = tid & 63;
  const int cl = l & 15, rq = l >> 4;
  const short* kgb = kg + (size_t)bh * 16384;
  const short* vgb = vg + (size_t)bh * 16384;
  #pragma unroll
  for (int i = 0; i < 2; ++i) {
    int slot = i * 1024 + tid;
    int row = slot >> 3, g = slot & 7;
    gll16(kgb + row * 64 + (g ^ (row & 7)) * 8, &Ks[slot * 8]);
  }
  #pragma unroll
  for (int i = 0; i < 2; ++i) {
    int slot = i * 1024 + tid;
    int row = slot >> 5, g = slot & 31;
    int gs = (g & 24) | ((g ^ row) & 7);
    gll16(vgb + row * 256 + gs * 8, &Vs[slot * 8]);
  }
  const int qrow = w * 16 + cl;
  const bf16x8* qp = (const bf16x8*)(qg + ((size_t)bh * 256 + qrow) * 64 + rq * 8);
  bf16x8 qf0 = qp[0], qf1 = qp[4];
  const int b = bh / 6, hh = bh - b * 6;
  __syncthreads();

  f32x4 s[16] = {};
  #pragma unroll
  for (int c = 0; c < 16; ++c) {
    int srow = c * 16 + cl;
    bf16x8 k0 = *(const bf16x8*)&Ks[srow * 64 + ((rq ^ (srow & 7)) * 8)];
    bf16x8 k1 = *(const bf16x8*)&Ks[srow * 64 + (((4 + rq) ^ (srow & 7)) * 8)];
    s[c] = MFMA16(k0, qf0, s[c]);
    s[c] = MFMA16(k1, qf1, s[c]);
  }
  float mr[8];
  #pragma unroll
  for (int c = 0; c < 8; ++c)
    mr[c] = fmaxf(fmaxf(fmaxf(s[2*c][0], s[2*c][1]), fmaxf(s[2*c][2], s[2*c][3])),
                  fmaxf(fmaxf(s[2*c+1][0], s[2*c+1][1]), fmaxf(s[2*c+1][2], s[2*c+1][3])));
  float m = fmaxf(fmaxf(fmaxf(mr[0], mr[1]), fmaxf(mr[2], mr[3])),
                  fmaxf(fmaxf(mr[4], mr[5]), fmaxf(mr[6], mr[7])));
  m = fmaxf(m, __shfl_xor(m, 16));
  m = fmaxf(m, __shfl_xor(m, 32));
  float tc[16];
  #pragma unroll
  for (int c = 0; c < 16; ++c) {
    #pragma unroll
    for (int r = 0; r < 4; ++r) s[c][r] = __expf(s[c][r] - m);
    tc[c] = (s[c][0] + s[c][1]) + (s[c][2] + s[c][3]);
  }
  float t = ((tc[0]+tc[1])+(tc[2]+tc[3])) + ((tc[4]+tc[5])+(tc[6]+tc[7]))
          + ((tc[8]+tc[9])+(tc[10]+tc[11])) + ((tc[12]+tc[13])+(tc[14]+tc[15]));
  t += __shfl_xor(t, 16);
  t += __shfl_xor(t, 32);
  const float inv = 1.f / t;   // for qrow = cl

  f32x4 oacc[4] = {};
  const int idx1 = (((2 * rq) & 3) * 16 + cl) << 2;
  const int idx2 = (((2 * rq + 1) & 3) * 16 + cl) << 2;
  const bool up = rq >= 2;
  #pragma unroll
  for (int ch = 0; ch < 8; ++ch) {
    int X0 = (int)cvtpk(s[2*ch][0], s[2*ch][1]);
    int X1 = (int)cvtpk(s[2*ch][2], s[2*ch][3]);
    int X2 = (int)cvtpk(s[2*ch+1][0], s[2*ch+1][1]);
    int X3 = (int)cvtpk(s[2*ch+1][2], s[2*ch+1][3]);
    int lo0 = __builtin_amdgcn_ds_bpermute(idx1, X0);
    int lo1 = __builtin_amdgcn_ds_bpermute(idx1, X1);
    int hi0 = __builtin_amdgcn_ds_bpermute(idx1, X2);
    int hi1 = __builtin_amdgcn_ds_bpermute(idx1, X3);
    int lo2 = __builtin_amdgcn_ds_bpermute(idx2, X0);
    int lo3 = __builtin_amdgcn_ds_bpermute(idx2, X1);
    int hi2 = __builtin_amdgcn_ds_bpermute(idx2, X2);
    int hi3 = __builtin_amdgcn_ds_bpermute(idx2, X3);
    u32x4 words;
    words[0] = (unsigned)(up ? hi0 : lo0);
    words[1] = (unsigned)(up ? hi1 : lo1);
    words[2] = (unsigned)(up ? hi2 : lo2);
    words[3] = (unsigned)(up ? hi3 : lo3);
    bf16x8 pa = __builtin_bit_cast(bf16x8, words);
    #pragma unroll
    for (int n = 0; n < 4; ++n) {
      int vrow = n * 16 + cl;
      int gg = ch * 4 + rq;
      int gs = (gg & 24) | ((gg ^ vrow) & 7);
      bf16x8 vf = *(const bf16x8*)&Vs[vrow * 256 + gs * 8];
      oacc[n] = MFMA16(pa, vf, oacc[n]);
    }
  }
  float invr[4];
  #pragma unroll
  for (int r = 0; r < 4; ++r) invr[r] = __shfl(inv, 4 * rq + r);
  #pragma unroll
  for (int n = 0; n < 4; ++n) {
    #pragma unroll
    for (int r = 0; r < 4; ++r) {
      int trow = w * 16 + 4 * rq + r;
      og[((size_t)(b * 256 + trow)) * 384 + hh * 64 + n * 16 + cl] =
          (short)f2b(oacc[n][r] * invr[r]);
    }
  }
}

// ---------------- host ----------------
extern "C" void kernel_launch(void* const* d_in, const int* in_sizes, int n_in,
                              void* d_out, int out_size, void* d_ws, size_t ws_size,
                              hipStream_t stream) {
  const float* x   = (const float*)d_in[0];
  const float* Wq  = (const float*)d_in[1];
  const float* Wk  = (const float*)d_in[2];
  const float* Wv  = (const float*)d_in[3];
  const float* Wo  = (const float*)d_in[4];
  const float* bo  = (const float*)d_in[5];
  const float* W1  = (const float*)d_in[6];
  const float* b1  = (const float*)d_in[7];
  const float* W2  = (const float*)d_in[8];
  const float* b2  = (const float*)d_in[9];
  const float* g1  = (const float*)d_in[10];
  const float* be1 = (const float*)d_in[11];
  const float* g2  = (const float*)d_in[12];
  const float* be2 = (const float*)d_in[13];

  char* ws = (char*)d_ws;
  short* wqkvT = (short*)(ws);                 //  884736 B (q sector pre-scaled)
  short* woT   = (short*)(ws + 884736);        //  294912 B
  short* w1T   = (short*)(ws + 1179648);       // 1179648 B
  short* w2T   = (short*)(ws + 2359296);       // 1179648 B
  short* bufA  = (short*)(ws + 3538944);       // shared region (shorts)
  short* h  = bufA;                            // LN1 out [0, 25165824)
  short* q  = bufA + 25165824;                 // [B,H,T,D]
  short* k  = bufA + 50331648;                 // [B,H,T,D]
  short* v  = bufA + 75497472;                 // [B,H,D,T]
  short* o  = bufA;                            // attn out, overlays h
  short* h2 = bufA + 25165824;                 // LN2 out, overlays q (dead)
  float* out = (float*)d_out;                  // residual stream after Wo

  prep_kernel<<<6912, 256, 0, stream>>>(Wq, Wk, Wv, Wo, W1, W2, wqkvT, woT, w1T, w2T);
  ln_kernel<<<16384, 256, 0, stream>>>(x, g1, be1, h);
  // QKV: [65536,384] x [1152,384]^T -> q,k,v   grid 9x256
  gemm_bt<0><<<9 * 256, 512, 0, stream>>>(h, wqkvT, 384, 6, 1152, 9,
      nullptr, nullptr, nullptr, q, k, v);
  attn_kernel<<<1536, 1024, 0, stream>>>(q, k, v, o);
  // Wo: out = o @ Wo + bo + x   grid 3x256
  gemm_bt<1><<<3 * 256, 512, 0, stream>>>(o, woT, 384, 6, 384, 3,
      bo, x, out, nullptr, nullptr, nullptr);
  ln_kernel<<<16384, 256, 0, stream>>>(out, g2, be2, h2);
  // fused FF: out += relu(h2 @ W1 + b1) @ W2 + b2
  ff_fused<<<1024, 512, 0, stream>>>(h2, w1T, w2T, b1, b2, out);
}

// Round 11
// 514.903 us; speedup vs baseline: 1.4122x; 1.1457x over previous
//
#include <hip/hip_runtime.h>

typedef __attribute__((ext_vector_type(8))) short bf16x8;
typedef __attribute__((ext_vector_type(4))) float f32x4;
typedef __attribute__((ext_vector_type(4))) unsigned short u16x4;
typedef __attribute__((ext_vector_type(4))) unsigned int u32x4;

#define DEVFN static __device__ __forceinline__

DEVFN unsigned short f2b(float f) {   // f32 -> bf16, round-to-nearest-even
  union { float f; unsigned u; } x; x.f = f;
  unsigned r = x.u + 0x7FFFu + ((x.u >> 16) & 1u);
  return (unsigned short)(r >> 16);
}

DEVFN unsigned cvtpk(float lo, float hi) {  // {bf16(hi)<<16 | bf16(lo)}
  unsigned r;
  asm("v_cvt_pk_bf16_f32 %0, %1, %2" : "=v"(r) : "v"(lo), "v"(hi));
  return r;
}

DEVFN void gll16(const void* g, void* l) {  // async global->LDS, 16B per lane
  __builtin_amdgcn_global_load_lds(
      (const __attribute__((address_space(1))) unsigned int*)g,
      (__attribute__((address_space(3))) unsigned int*)l, 16, 0, 0);
}

#define MFMA16(a, b, c) __builtin_amdgcn_mfma_f32_16x16x32_bf16((a), (b), (c), 0, 0, 0)

// ---------------- prep: cast + transpose weights to bf16 ----------------
// wqkvT [1152][384] (q sector pre-scaled by 0.125), woT, w1T, w2T
__global__ __launch_bounds__(256) void prep_kernel(
    const float* __restrict__ Wq, const float* __restrict__ Wk, const float* __restrict__ Wv,
    const float* __restrict__ Wo, const float* __restrict__ W1, const float* __restrict__ W2,
    short* __restrict__ wqkvT, short* __restrict__ woT,
    short* __restrict__ w1T, short* __restrict__ w2T)
{
  int idx = blockIdx.x * 256 + threadIdx.x;
  if (idx < 442368) {
    int n = idx / 384, kk = idx - n * 384;
    int sec = n / 384, ww = n - sec * 384;
    const float* s = sec == 0 ? Wq : (sec == 1 ? Wk : Wv);
    float sc = (sec == 0) ? 0.125f : 1.0f;
    wqkvT[idx] = (short)f2b(s[kk * 384 + ww] * sc);
  } else if (idx < 589824) {
    int j = idx - 442368;
    int n = j / 384, kk = j - n * 384;
    woT[j] = (short)f2b(Wo[kk * 384 + n]);
  } else if (idx < 1179648) {
    int j = idx - 589824;
    int n = j / 384, kk = j - n * 384;
    w1T[j] = (short)f2b(W1[kk * 1536 + n]);
  } else if (idx < 1769472) {
    int j = idx - 1179648;
    int n = j / 1536, kk = j - n * 1536;
    w2T[j] = (short)f2b(W2[kk * 384 + n]);
  }
}

// ---------------- LayerNorm: f32 in -> bf16 out, 1 wave per row of 384 ----
__global__ __launch_bounds__(256) void ln_kernel(
    const float* __restrict__ x, const float* __restrict__ g, const float* __restrict__ b,
    short* __restrict__ out)
{
  int row = blockIdx.x * 4 + (threadIdx.x >> 6);
  int l = threadIdx.x & 63;
  const float* xr = x + (size_t)row * 384;
  float v[6], s = 0.f, s2 = 0.f;
  #pragma unroll
  for (int i = 0; i < 6; ++i) { v[i] = xr[l + 64 * i]; s += v[i]; s2 += v[i] * v[i]; }
  #pragma unroll
  for (int m = 1; m < 64; m <<= 1) { s += __shfl_xor(s, m); s2 += __shfl_xor(s2, m); }
  float mu = s * (1.f / 384.f);
  float rs = rsqrtf(s2 * (1.f / 384.f) - mu * mu + 1e-5f);
  short* orow = out + (size_t)row * 384;
  #pragma unroll
  for (int i = 0; i < 6; ++i) {
    int c = l + 64 * i;
    orow[c] = (short)f2b((v[i] - mu) * rs * g[c] + b[c]);
  }
}

// ---------------- GEMM: C[M,N] = A[M,K] * BT[N,K]^T, bf16 MFMA ------------
// 256x128 tile, BK=64, 512 threads = 8 waves (4x2), wave = 64x64 (4x4 frags).
// EPI 0: QKV split (weights pre-scaled; v stored [B,H,D,T])   [R5-exact]
// EPI 1: f32 out = acc + bias[col] + resid[row,col]   (fout may alias resid)
// EPI 2: bf16 out = relu(acc + bias[col])
template<int EPI>
__global__ __launch_bounds__(512) void gemm_bt(
    const short* __restrict__ A, const short* __restrict__ BT,
    int K, int kt, int N, int nx,
    const float* __restrict__ bias, const float* __restrict__ resid,
    float* __restrict__ fout, short* __restrict__ bout,
    short* __restrict__ qb, short* __restrict__ kb, short* __restrict__ vb)
{
  __shared__ short As[256 * 64];
  __shared__ short Bs[128 * 64];
  const int tid = threadIdx.x;
  const int l = tid & 63, w = tid >> 6;
  const int cl = l & 15, rq = l >> 4;
  const int wr = (w >> 1) * 64, wc = (w & 1) * 64;

  // bijective XCD-chunk swizzle
  const int nwg = gridDim.x, bid = blockIdx.x;
  const int q8 = nwg >> 3, r8 = nwg & 7;
  const int xcd = bid & 7, ii = bid >> 3;
  const int wg = (xcd < r8) ? xcd * (q8 + 1) + ii : r8 * (q8 + 1) + (xcd - r8) * q8 + ii;
  const int bx = wg % nx, by = wg / nx;

  const int m0 = by * 256, n0 = bx * 128;
  const short* Ab = A + (size_t)m0 * K;
  const short* Bb = BT + (size_t)n0 * K;

  f32x4 acc[4][4] = {};

  for (int ks = 0; ks < kt; ++ks) {
    const int k0 = ks * 64;
    __syncthreads();
    #pragma unroll
    for (int i = 0; i < 4; ++i) {
      int slot = i * 512 + tid;
      int row = slot >> 3, g = slot & 7;
      int gs = g ^ (row & 7);
      gll16(Ab + (size_t)row * K + k0 + gs * 8, &As[slot * 8]);
    }
    #pragma unroll
    for (int i = 0; i < 2; ++i) {
      int slot = i * 512 + tid;
      int row = slot >> 3, g = slot & 7;
      int gs = g ^ (row & 7);
      gll16(Bb + (size_t)row * K + k0 + gs * 8, &Bs[slot * 8]);
    }
    __syncthreads();
    #pragma unroll
    for (int kk = 0; kk < 2; ++kk) {
      bf16x8 af[4], bfr[4];
      #pragma unroll
      for (int m = 0; m < 4; ++m) {
        int row = wr + m * 16 + cl;
        af[m] = *(const bf16x8*)&As[row * 64 + (((kk * 4 + rq) ^ (row & 7)) * 8)];
      }
      #pragma unroll
      for (int n = 0; n < 4; ++n) {
        int row = wc + n * 16 + cl;
        bfr[n] = *(const bf16x8*)&Bs[row * 64 + (((kk * 4 + rq) ^ (row & 7)) * 8)];
      }
      #pragma unroll
      for (int m = 0; m < 4; ++m)
        #pragma unroll
        for (int n = 0; n < 4; ++n)
          acc[m][n] = MFMA16(af[m], bfr[n], acc[m][n]);
    }
  }

  const int gr0 = m0 + wr, gc0 = n0 + wc;
  #pragma unroll
  for (int m = 0; m < 4; ++m) {
    #pragma unroll
    for (int n = 0; n < 4; ++n) {
      int col = gc0 + n * 16 + cl;
      int rbase = gr0 + m * 16 + rq * 4;
      if constexpr (EPI == 0) {
        int sec = col / 384;
        int wcol = col - sec * 384;
        int hh = wcol >> 6, d = wcol & 63;
        int bidx = rbase >> 8, t0 = rbase & 255;
        if (sec == 2) {
          u16x4 pk;
          #pragma unroll
          for (int r = 0; r < 4; ++r) pk[r] = f2b(acc[m][n][r]);
          *(u16x4*)&vb[((size_t)(bidx * 6 + hh) * 64 + d) * 256 + t0] = pk;
        } else {
          short* dst = (sec == 0) ? qb : kb;
          #pragma unroll
          for (int r = 0; r < 4; ++r)
            dst[((size_t)(bidx * 6 + hh) * 256 + t0 + r) * 64 + d] = (short)f2b(acc[m][n][r]);
        }
      } else if constexpr (EPI == 1) {
        #pragma unroll
        for (int r = 0; r < 4; ++r) {
          size_t ix = (size_t)(rbase + r) * N + col;
          fout[ix] = acc[m][n][r] + bias[col] + resid[ix];
        }
      } else {
        #pragma unroll
        for (int r = 0; r < 4; ++r)
          bout[(size_t)(rbase + r) * N + col] = (short)f2b(fmaxf(acc[m][n][r] + bias[col], 0.f));
      }
    }
  }
}

// ---------------- Wo GEMM + residual + LayerNorm2 fused -------------------
// out = o @ Wo + bo + x ; h2 = LN(out, g2, be2)
// 128x384 tile (full N -> block owns complete rows). 512 thr = 8 waves
// (2 row-waves x 4 col-waves); wave = 64 rows x 96 cols (4x6 frags).
// Row stats: per-lane partial over 6 frags -> shfl_xor over 16 cl-lanes ->
// LDS[row][wn] -> one pass computes mu/rs -> normalize + write h2 bf16.
__global__ __launch_bounds__(512) void wo_ln_kernel(
    const short* __restrict__ A,       // o [65536][384] bf16
    const short* __restrict__ BT,      // woT [384][384] bf16
    const float* __restrict__ bo, const float* __restrict__ x,
    const float* __restrict__ g2, const float* __restrict__ be2,
    float* __restrict__ out, short* __restrict__ h2)
{
  __shared__ short As[128 * 64];
  __shared__ short Bs[384 * 64];
  __shared__ float redS[128][4], redQ[128][4];
  __shared__ float redMu[128], redRs[128];
  const int tid = threadIdx.x;
  const int l = tid & 63, w = tid >> 6;
  const int cl = l & 15, rq = l >> 4;
  const int wm = w >> 2, wn = w & 3;

  // XCD swizzle (nwg = 512, divisible by 8)
  const int nwg = gridDim.x, bid = blockIdx.x;
  const int q8 = nwg >> 3;
  const int wg = (bid & 7) * q8 + (bid >> 3);
  const int m0 = wg * 128;
  const short* Ab = A + (size_t)m0 * 384;

  f32x4 acc[4][6] = {};

  for (int ks = 0; ks < 6; ++ks) {
    const int k0 = ks * 64;
    __syncthreads();
    #pragma unroll
    for (int i = 0; i < 2; ++i) {
      int slot = i * 512 + tid;
      int row = slot >> 3, g = slot & 7;
      int gs = g ^ (row & 7);
      gll16(Ab + (size_t)row * 384 + k0 + gs * 8, &As[slot * 8]);
    }
    #pragma unroll
    for (int i = 0; i < 6; ++i) {
      int slot = i * 512 + tid;
      int row = slot >> 3, g = slot & 7;
      int gs = g ^ (row & 7);
      gll16(BT + (size_t)row * 384 + k0 + gs * 8, &Bs[slot * 8]);
    }
    __syncthreads();
    #pragma unroll
    for (int kk = 0; kk < 2; ++kk) {
      bf16x8 af[4], bfr[6];
      #pragma unroll
      for (int m = 0; m < 4; ++m) {
        int row = wm * 64 + m * 16 + cl;
        af[m] = *(const bf16x8*)&As[row * 64 + (((kk * 4 + rq) ^ (row & 7)) * 8)];
      }
      #pragma unroll
      for (int n = 0; n < 6; ++n) {
        int row = wn * 96 + n * 16 + cl;
        bfr[n] = *(const bf16x8*)&Bs[row * 64 + (((kk * 4 + rq) ^ (row & 7)) * 8)];
      }
      #pragma unroll
      for (int m = 0; m < 4; ++m)
        #pragma unroll
        for (int n = 0; n < 6; ++n)
          acc[m][n] = MFMA16(af[m], bfr[n], acc[m][n]);
    }
  }

  // epilogue 1: val = acc + bo + x ; write out ; row partial sums
  #pragma unroll
  for (int m = 0; m < 4; ++m) {
    #pragma unroll
    for (int r = 0; r < 4; ++r) {
      int lrow = wm * 64 + m * 16 + rq * 4 + r;
      float p = 0.f, qs = 0.f;
      #pragma unroll
      for (int n = 0; n < 6; ++n) {
        int col = wn * 96 + n * 16 + cl;
        size_t ix = (size_t)(m0 + lrow) * 384 + col;
        float v = acc[m][n][r] + bo[col] + x[ix];
        acc[m][n][r] = v;
        out[ix] = v;
        p += v; qs += v * v;
      }
      #pragma unroll
      for (int msk = 1; msk < 16; msk <<= 1) {
        p += __shfl_xor(p, msk);
        qs += __shfl_xor(qs, msk);
      }
      if (cl == 0) { redS[lrow][wn] = p; redQ[lrow][wn] = qs; }
    }
  }
  __syncthreads();
  if (tid < 128) {
    float S = redS[tid][0] + redS[tid][1] + redS[tid][2] + redS[tid][3];
    float Q = redQ[tid][0] + redQ[tid][1] + redQ[tid][2] + redQ[tid][3];
    float mu = S * (1.f / 384.f);
    redMu[tid] = mu;
    redRs[tid] = rsqrtf(Q * (1.f / 384.f) - mu * mu + 1e-5f);
  }
  __syncthreads();
  // epilogue 2: normalize + write h2 bf16
  #pragma unroll
  for (int m = 0; m < 4; ++m) {
    #pragma unroll
    for (int r = 0; r < 4; ++r) {
      int lrow = wm * 64 + m * 16 + rq * 4 + r;
      float mu = redMu[lrow], rs = redRs[lrow];
      #pragma unroll
      for (int n = 0; n < 6; ++n) {
        int col = wn * 96 + n * 16 + cl;
        h2[(size_t)(m0 + lrow) * 384 + col] =
            (short)f2b((acc[m][n][r] - mu) * rs * g2[col] + be2[col]);
      }
    }
  }
}

// ---------------- attention: 1 block = ONE (b,h), 1024 thr = 16 waves -----
// (verbatim from R5, passing)
__global__ __launch_bounds__(1024) void attn_kernel(
    const short* __restrict__ qg, const short* __restrict__ kg,
    const short* __restrict__ vg, short* __restrict__ og)
{
  __shared__ short Ks[256 * 64];   // [s][d], swizzled (8 granules/row)
  __shared__ short Vs[64 * 256];   // [d][s], swizzled (32 granules/row, low3)
  const int tid = threadIdx.x;
  const int bh = blockIdx.x;
  const int w = tid >> 6, l = tid & 63;
  const int cl = l & 15, rq = l >> 4;
  const short* kgb = kg + (size_t)bh * 16384;
  const short* vgb = vg + (size_t)bh * 16384;
  #pragma unroll
  for (int i = 0; i < 2; ++i) {
    int slot = i * 1024 + tid;
    int row = slot >> 3, g = slot & 7;
    gll16(kgb + row * 64 + (g ^ (row & 7)) * 8, &Ks[slot * 8]);
  }
  #pragma unroll
  for (int i = 0; i < 2; ++i) {
    int slot = i * 1024 + tid;
    int row = slot >> 5, g = slot & 31;
    int gs = (g & 24) | ((g ^ row) & 7);
    gll16(vgb + row * 256 + gs * 8, &Vs[slot * 8]);
  }
  const int qrow = w * 16 + cl;
  const bf16x8* qp = (const bf16x8*)(qg + ((size_t)bh * 256 + qrow) * 64 + rq * 8);
  bf16x8 qf0 = qp[0], qf1 = qp[4];
  const int b = bh / 6, hh = bh - b * 6;
  __syncthreads();

  f32x4 s[16] = {};
  #pragma unroll
  for (int c = 0; c < 16; ++c) {
    int srow = c * 16 + cl;
    bf16x8 k0 = *(const bf16x8*)&Ks[srow * 64 + ((rq ^ (srow & 7)) * 8)];
    bf16x8 k1 = *(const bf16x8*)&Ks[srow * 64 + (((4 + rq) ^ (srow & 7)) * 8)];
    s[c] = MFMA16(k0, qf0, s[c]);
    s[c] = MFMA16(k1, qf1, s[c]);
  }
  float mr[8];
  #pragma unroll
  for (int c = 0; c < 8; ++c)
    mr[c] = fmaxf(fmaxf(fmaxf(s[2*c][0], s[2*c][1]), fmaxf(s[2*c][2], s[2*c][3])),
                  fmaxf(fmaxf(s[2*c+1][0], s[2*c+1][1]), fmaxf(s[2*c+1][2], s[2*c+1][3])));
  float m = fmaxf(fmaxf(fmaxf(mr[0], mr[1]), fmaxf(mr[2], mr[3])),
                  fmaxf(fmaxf(mr[4], mr[5]), fmaxf(mr[6], mr[7])));
  m = fmaxf(m, __shfl_xor(m, 16));
  m = fmaxf(m, __shfl_xor(m, 32));
  float tc[16];
  #pragma unroll
  for (int c = 0; c < 16; ++c) {
    #pragma unroll
    for (int r = 0; r < 4; ++r) s[c][r] = __expf(s[c][r] - m);
    tc[c] = (s[c][0] + s[c][1]) + (s[c][2] + s[c][3]);
  }
  float t = ((tc[0]+tc[1])+(tc[2]+tc[3])) + ((tc[4]+tc[5])+(tc[6]+tc[7]))
          + ((tc[8]+tc[9])+(tc[10]+tc[11])) + ((tc[12]+tc[13])+(tc[14]+tc[15]));
  t += __shfl_xor(t, 16);
  t += __shfl_xor(t, 32);
  const float inv = 1.f / t;   // for qrow = cl

  f32x4 oacc[4] = {};
  const int idx1 = (((2 * rq) & 3) * 16 + cl) << 2;
  const int idx2 = (((2 * rq + 1) & 3) * 16 + cl) << 2;
  const bool up = rq >= 2;
  #pragma unroll
  for (int ch = 0; ch < 8; ++ch) {
    int X0 = (int)cvtpk(s[2*ch][0], s[2*ch][1]);
    int X1 = (int)cvtpk(s[2*ch][2], s[2*ch][3]);
    int X2 = (int)cvtpk(s[2*ch+1][0], s[2*ch+1][1]);
    int X3 = (int)cvtpk(s[2*ch+1][2], s[2*ch+1][3]);
    int lo0 = __builtin_amdgcn_ds_bpermute(idx1, X0);
    int lo1 = __builtin_amdgcn_ds_bpermute(idx1, X1);
    int hi0 = __builtin_amdgcn_ds_bpermute(idx1, X2);
    int hi1 = __builtin_amdgcn_ds_bpermute(idx1, X3);
    int lo2 = __builtin_amdgcn_ds_bpermute(idx2, X0);
    int lo3 = __builtin_amdgcn_ds_bpermute(idx2, X1);
    int hi2 = __builtin_amdgcn_ds_bpermute(idx2, X2);
    int hi3 = __builtin_amdgcn_ds_bpermute(idx2, X3);
    u32x4 words;
    words[0] = (unsigned)(up ? hi0 : lo0);
    words[1] = (unsigned)(up ? hi1 : lo1);
    words[2] = (unsigned)(up ? hi2 : lo2);
    words[3] = (unsigned)(up ? hi3 : lo3);
    bf16x8 pa = __builtin_bit_cast(bf16x8, words);
    #pragma unroll
    for (int n = 0; n < 4; ++n) {
      int vrow = n * 16 + cl;
      int gg = ch * 4 + rq;
      int gs = (gg & 24) | ((gg ^ vrow) & 7);
      bf16x8 vf = *(const bf16x8*)&Vs[vrow * 256 + gs * 8];
      oacc[n] = MFMA16(pa, vf, oacc[n]);
    }
  }
  float invr[4];
  #pragma unroll
  for (int r = 0; r < 4; ++r) invr[r] = __shfl(inv, 4 * rq + r);
  #pragma unroll
  for (int n = 0; n < 4; ++n) {
    #pragma unroll
    for (int r = 0; r < 4; ++r) {
      int trow = w * 16 + 4 * rq + r;
      og[((size_t)(b * 256 + trow)) * 384 + hh * 64 + n * 16 + cl] =
          (short)f2b(oacc[n][r] * invr[r]);
    }
  }
}

// ---------------- host ----------------
extern "C" void kernel_launch(void* const* d_in, const int* in_sizes, int n_in,
                              void* d_out, int out_size, void* d_ws, size_t ws_size,
                              hipStream_t stream) {
  const float* x   = (const float*)d_in[0];
  const float* Wq  = (const float*)d_in[1];
  const float* Wk  = (const float*)d_in[2];
  const float* Wv  = (const float*)d_in[3];
  const float* Wo  = (const float*)d_in[4];
  const float* bo  = (const float*)d_in[5];
  const float* W1  = (const float*)d_in[6];
  const float* b1  = (const float*)d_in[7];
  const float* W2  = (const float*)d_in[8];
  const float* b2  = (const float*)d_in[9];
  const float* g1  = (const float*)d_in[10];
  const float* be1 = (const float*)d_in[11];
  const float* g2  = (const float*)d_in[12];
  const float* be2 = (const float*)d_in[13];

  char* ws = (char*)d_ws;
  short* wqkvT = (short*)(ws);                 //  884736 B (q sector pre-scaled)
  short* woT   = (short*)(ws + 884736);        //  294912 B
  short* w1T   = (short*)(ws + 1179648);       // 1179648 B
  short* w2T   = (short*)(ws + 2359296);       // 1179648 B
  short* bufA  = (short*)(ws + 3538944);       // 201326592 B shared region (shorts)
  short* h  = bufA;                            // LN1 out [0, 25165824)
  short* q  = bufA + 25165824;                 // [B,H,T,D]
  short* k  = bufA + 50331648;                 // [B,H,T,D]
  short* v  = bufA + 75497472;                 // [B,H,D,T]
  short* o  = bufA;                            // attn out, overlays h
  short* h2 = bufA + 25165824;                 // LN2 out (wo_ln), overlays q
  short* act = bufA + 50331648;                // FF1 act (32768 rows), overlays k,v
  float* out = (float*)d_out;                  // residual stream after Wo

  prep_kernel<<<6912, 256, 0, stream>>>(Wq, Wk, Wv, Wo, W1, W2, wqkvT, woT, w1T, w2T);
  ln_kernel<<<16384, 256, 0, stream>>>(x, g1, be1, h);
  // QKV: [65536,384] x [1152,384]^T -> q,k,v   grid 9x256
  gemm_bt<0><<<9 * 256, 512, 0, stream>>>(h, wqkvT, 384, 6, 1152, 9,
      nullptr, nullptr, nullptr, nullptr, q, k, v);
  attn_kernel<<<1536, 1024, 0, stream>>>(q, k, v, o);
  // Wo + residual + LN2 fused: out = o@Wo + bo + x ; h2 = LN(out)
  wo_ln_kernel<<<512, 512, 0, stream>>>(o, woT, bo, x, g2, be2, out, h2);
  // FF (unfused two-chunk, R5 structure)
  for (int c = 0; c < 2; ++c) {
    const size_t roff = (size_t)c * 32768 * 384;
    gemm_bt<2><<<12 * 128, 512, 0, stream>>>(h2 + roff, w1T, 384, 6, 1536, 12,
        b1, nullptr, nullptr, act, nullptr, nullptr, nullptr);
    gemm_bt<1><<<3 * 128, 512, 0, stream>>>(act, w2T, 1536, 24, 384, 3,
        b2, out + roff, out + roff, nullptr, nullptr, nullptr, nullptr);
  }
}